// Round 1
// baseline (1321.746 us; speedup 1.0000x reference)
//
#include <hip/hip_runtime.h>
#include <stdint.h>

// Problem constants (fixed by reference: N=8192 samples, D=4096 dim)
#define NN 8192
#define DD 4096
#define NBLK 64        // NN / 128 row/col blocks
#define BK 32          // K-step
#define NT (DD / BK)   // 128 K-steps
#define LDSTILE 8192   // 128 rows x 32 bf16 = 8 KB per tile
#define LDSBUF (4 * LDSTILE)  // A_re, A_im, B_re, B_im

typedef short bf16x8 __attribute__((ext_vector_type(8)));
typedef float f32x4  __attribute__((ext_vector_type(4)));
typedef uint16_t u16x4 __attribute__((ext_vector_type(4)));

// async global->LDS, 16B per lane. LDS dest must be wave-uniform base + lane*16.
#define GLOAD(g, l) __builtin_amdgcn_global_load_lds( \
    (__attribute__((address_space(1))) uint32_t*)(void*)(size_t)(g), \
    (__attribute__((address_space(3))) uint32_t*)(void*)(l), 16, 0, 0)

__device__ __forceinline__ uint16_t f2bf(float x) {
  // round-to-nearest-even fp32 -> bf16 (inputs are finite gaussians; no NaN care)
  uint32_t u = __builtin_bit_cast(uint32_t, x);
  return (uint16_t)((u + 0x7fffu + ((u >> 16) & 1u)) >> 16);
}

__global__ void convert_kernel(const float* __restrict__ re, const float* __restrict__ im,
                               uint16_t* __restrict__ reb, uint16_t* __restrict__ imb) {
  size_t i = (size_t)blockIdx.x * blockDim.x + threadIdx.x;
  const size_t stride = (size_t)gridDim.x * blockDim.x;
  const size_t total = (size_t)NN * DD / 4;
  for (; i < total; i += stride) {
    float4 r = ((const float4*)re)[i];
    float4 m = ((const float4*)im)[i];
    u16x4 rb = { f2bf(r.x), f2bf(r.y), f2bf(r.z), f2bf(r.w) };
    u16x4 mb = { f2bf(m.x), f2bf(m.y), f2bf(m.z), f2bf(m.w) };
    ((u16x4*)reb)[i] = rb;
    ((u16x4*)imb)[i] = mb;
  }
}

// One block computes one 128x128 tile of the Gram matrix for block-pair (bi, bj), bi <= bj.
// g_re = re_i . re_j^T + im_i . im_j^T ; g_im = im_i . re_j^T - re_i . im_j^T
// fid = g_re^2 + g_im^2 (symmetric -> mirrored to (bj,bi)); weights upper-tri thresholded.
__global__ __launch_bounds__(256, 2) void gram_kernel(
    const uint16_t* __restrict__ reb, const uint16_t* __restrict__ imb,
    float* __restrict__ wts, float* __restrict__ fidp) {
  __shared__ alignas(16) char lds[2 * LDSBUF];  // 64 KB, double buffered

  // linear block id -> (bi, bj) with bi <= bj; offset(bi) = bi*NBLK - bi*(bi-1)/2
  const int t = blockIdx.x;
  int bi = (int)(((float)(2 * NBLK + 1) -
                  sqrtf((float)((2 * NBLK + 1) * (2 * NBLK + 1) - 8 * t))) * 0.5f);
  if (bi < 0) bi = 0;
  if (bi > NBLK - 1) bi = NBLK - 1;
  while (bi > 0 && t < bi * NBLK - bi * (bi - 1) / 2) --bi;
  while (t >= (bi + 1) * NBLK - (bi + 1) * bi / 2) ++bi;
  const int bj = bi + (t - (bi * NBLK - bi * (bi - 1) / 2));

  const int brow = bi * 128, bcol = bj * 128;
  const int tid = threadIdx.x;
  const int lane = tid & 63;
  const int wid = tid >> 6;
  const int wr = wid >> 1, wc = wid & 1;  // 2x2 wave grid, 64x64 out per wave

  // staging: thread tid loads 16B chunks; row = tid>>2 (0..63, +64 second call), chunk = tid&3
  const int sr = tid >> 2;
  const int sc = (tid & 3) * 8;
  const uint16_t* gAre = reb + (size_t)(brow + sr) * DD + sc;
  const uint16_t* gAim = imb + (size_t)(brow + sr) * DD + sc;
  const uint16_t* gBre = reb + (size_t)(bcol + sr) * DD + sc;
  const uint16_t* gBim = imb + (size_t)(bcol + sr) * DD + sc;
  const size_t rowHalf = (size_t)64 * DD;

  f32x4 acc_re[4][4], acc_im[4][4];
  const f32x4 z4 = {0.f, 0.f, 0.f, 0.f};
#pragma unroll
  for (int m = 0; m < 4; ++m)
#pragma unroll
    for (int n = 0; n < 4; ++n) { acc_re[m][n] = z4; acc_im[m][n] = z4; }

  // fragment LDS byte offsets (within a tile): row=(wX*64 + f*16 + (lane&15)), kbyte=(lane>>4)*16
  const int fr = lane & 15;
  const int kg = lane >> 4;
  const int aoff = (wr * 64 + fr) * 64 + kg * 16;  // + m*1024
  const int boff = (wc * 64 + fr) * 64 + kg * 16;  // + n*1024

#define STAGE(step, buf)                                                        \
  do {                                                                          \
    const size_t koff = (size_t)(step) * BK;                                    \
    char* lb_ = lds + (buf) * LDSBUF + tid * 16;                                \
    GLOAD(gAre + koff,           lb_ + 0 * LDSTILE);                            \
    GLOAD(gAre + koff + rowHalf, lb_ + 0 * LDSTILE + 4096);                     \
    GLOAD(gAim + koff,           lb_ + 1 * LDSTILE);                            \
    GLOAD(gAim + koff + rowHalf, lb_ + 1 * LDSTILE + 4096);                     \
    GLOAD(gBre + koff,           lb_ + 2 * LDSTILE);                            \
    GLOAD(gBre + koff + rowHalf, lb_ + 2 * LDSTILE + 4096);                     \
    GLOAD(gBim + koff,           lb_ + 3 * LDSTILE);                            \
    GLOAD(gBim + koff + rowHalf, lb_ + 3 * LDSTILE + 4096);                     \
  } while (0)

  STAGE(0, 0);
  __syncthreads();

  for (int step = 0; step < NT; ++step) {
    if (step + 1 < NT) STAGE(step + 1, (step + 1) & 1);

    const char* lb = lds + (step & 1) * LDSBUF;
    bf16x8 ar[4], ai[4], arn[4], br[4], bim[4];
#pragma unroll
    for (int m = 0; m < 4; ++m) {
      ar[m] = *(const bf16x8*)(lb + 0 * LDSTILE + aoff + m * 1024);
      ai[m] = *(const bf16x8*)(lb + 1 * LDSTILE + aoff + m * 1024);
    }
#pragma unroll
    for (int n = 0; n < 4; ++n) {
      br[n]  = *(const bf16x8*)(lb + 2 * LDSTILE + boff + n * 1024);
      bim[n] = *(const bf16x8*)(lb + 3 * LDSTILE + boff + n * 1024);
    }
#pragma unroll
    for (int m = 0; m < 4; ++m) arn[m] = ar[m] ^ (short)0x8000;  // -re in bf16

#pragma unroll
    for (int m = 0; m < 4; ++m)
#pragma unroll
      for (int n = 0; n < 4; ++n) {
        acc_re[m][n] = __builtin_amdgcn_mfma_f32_16x16x32_bf16(ar[m],  br[n],  acc_re[m][n], 0, 0, 0);
        acc_re[m][n] = __builtin_amdgcn_mfma_f32_16x16x32_bf16(ai[m],  bim[n], acc_re[m][n], 0, 0, 0);
        acc_im[m][n] = __builtin_amdgcn_mfma_f32_16x16x32_bf16(ai[m],  br[n],  acc_im[m][n], 0, 0, 0);
        acc_im[m][n] = __builtin_amdgcn_mfma_f32_16x16x32_bf16(arn[m], bim[n], acc_im[m][n], 0, 0, 0);
      }

    __syncthreads();
  }

  // ---------------- epilogue ----------------
  // C/D layout (16x16x32): col = lane&15, row = (lane>>4)*4 + reg
  const int grow0 = brow + wr * 64 + kg * 4;  // + m*16 + j
  const int gcol0 = bcol + wc * 64 + fr;      // + n*16

#pragma unroll
  for (int m = 0; m < 4; ++m) {
#pragma unroll
    for (int n = 0; n < 4; ++n) {
      const int gc = gcol0 + n * 16;
      f32x4 fv;
#pragma unroll
      for (int j = 0; j < 4; ++j) {
        float gr = acc_re[m][n][j];
        float gi = acc_im[m][n][j];
        fv[j] = gr * gr + gi * gi;
      }
#pragma unroll
      for (int j = 0; j < 4; ++j) {
        const int grow = grow0 + m * 16 + j;
        const float f = fv[j];
        fidp[(size_t)grow * NN + gc] = f;
        float w = 0.0f;
        if (grow < gc) w = (f >= 0.8f) ? 1.0f : ((f >= 0.5f) ? 0.5f : 0.0f);
        wts[(size_t)grow * NN + gc] = w;
      }
      if (bi != bj) {
        // fid is symmetric: mirror tile, 4 rows contiguous at transposed address
        *(f32x4*)(fidp + (size_t)gc * NN + grow0 + m * 16) = fv;
      }
    }
  }

  if (bi != bj) {
    // mirror block (bj,bi) of weights is strictly lower-triangular -> all zeros
    const f32x4 zz = {0.f, 0.f, 0.f, 0.f};
    for (int i = tid; i < 4096; i += 256) {
      const int r = i >> 5, c4 = i & 31;
      *(f32x4*)(wts + (size_t)(bcol + r) * NN + brow + c4 * 4) = zz;
    }
  }
}

extern "C" void kernel_launch(void* const* d_in, const int* in_sizes, int n_in,
                              void* d_out, int out_size, void* d_ws, size_t ws_size,
                              hipStream_t stream) {
  const float* re = (const float*)d_in[0];
  const float* im = (const float*)d_in[1];
  float* out = (float*)d_out;

  uint16_t* reb = (uint16_t*)d_ws;                 // N*D bf16
  uint16_t* imb = reb + (size_t)NN * DD;           // N*D bf16  (total 128 MiB)

  convert_kernel<<<2048, 256, 0, stream>>>(re, im, reb, imb);

  const int nblocks = NBLK * (NBLK + 1) / 2;  // 2080 upper-tri block pairs
  gram_kernel<<<nblocks, 256, 0, stream>>>(reb, imb, out, out + (size_t)NN * NN);
}